// Round 13
// baseline (262.509 us; speedup 1.0000x reference)
//
#include <hip/hip_runtime.h>
#include <hip/hip_bf16.h>
#include <math.h>

#define NBATCH 512
#define TT 64
#define EMB 512
#define NHEADS 8
#define HDIM 64
#define MROWS (NBATCH * TT)          // 32768
#define ROWSTRIDE (TT * EMB)         // 32768 elems per batch row of a plane
#define WSEG 262144                  // 512*512 weight elems

// 1/sqrt(512) * log2(e): folded into Wq/bq so attn logits are in log2 domain
static constexpr float QSCALE = 0.0637587140f;

typedef __attribute__((ext_vector_type(8))) short short8v;  // 8 bf16 (4 VGPR)
typedef __attribute__((ext_vector_type(4))) float f32x4;

__device__ __forceinline__ unsigned short f2bf(float x) {
    union { float f; unsigned int u; } v; v.f = x;
    unsigned int r = v.u + 0x7fff + ((v.u >> 16) & 1);   // RNE
    return (unsigned short)(r >> 16);
}

// v_cvt_pk_bf16_f32: packs lo->bits[15:0], hi->bits[31:16], RNE
__device__ __forceinline__ unsigned int cvtpk(float lo, float hi) {
    unsigned int r;
    asm("v_cvt_pk_bf16_f32 %0, %1, %2" : "=v"(r) : "v"(lo), "v"(hi));
    return r;
}

__device__ __forceinline__ void gl16(const void* g, void* l) {
    __builtin_amdgcn_global_load_lds(
        (const __attribute__((address_space(1))) unsigned int*)g,
        (__attribute__((address_space(3))) unsigned int*)l, 16, 0, 0);
}

// ---------------------------------------------------------------------------
// weights fp32 -> bf16 (4 MB); seg 0 (Wq) pre-scaled by QSCALE
// ---------------------------------------------------------------------------
__global__ __launch_bounds__(256) void cvtw(
    const float* __restrict__ w0, const float* __restrict__ w1,
    const float* __restrict__ w2, const float* __restrict__ w3,
    unsigned short* __restrict__ dst)
{
    const int seg = blockIdx.y;
    const float* src = (seg == 0) ? w0 : (seg == 1) ? w1 : (seg == 2) ? w2 : w3;
    const float sc = (seg == 0) ? QSCALE : 1.0f;
    const size_t i = (size_t)blockIdx.x * 256 + threadIdx.x;   // x4 elems
    float4 v = reinterpret_cast<const float4*>(src)[i];
    ushort4 r;
    r.x = f2bf(v.x * sc); r.y = f2bf(v.y * sc); r.z = f2bf(v.z * sc); r.w = f2bf(v.w * sc);
    reinterpret_cast<ushort4*>(dst + (size_t)seg * WSEG)[i] = r;
}

// ---------------------------------------------------------------------------
// Merged q/k/v projections, fused fp32->bf16 A conversion.
// FULL-N, SMALL-BM blocks: one block = 64 m-rows x all 512 n.
//   -> A read from HBM exactly once (fused convert, no cvt3 pass)
//   -> LDS only 37 KB -> ~4 blocks/CU -> barrier drains overlap across
//      blocks (m114), unlike the 1-block/CU rounds 11/12.
// 512 thr / 8 waves; wave w owns the 64m x 64n stripe at col 64w; acc[4][4].
// Per iter (BK=32): W chunk 512x32 bf16 via 4 gl16/thread (linear layout);
// A chunk 64x32: one float4/thread -> 2 cvtpk -> ds_write_b64 into
// stride-40-padded rows (2-way bank reads).
// ---------------------------------------------------------------------------
__global__ __launch_bounds__(512) void gemm_proj3(
    const float* __restrict__ A0, const float* __restrict__ A1,
    const float* __restrict__ A2, const unsigned short* __restrict__ Wb,
    const float* __restrict__ b0, const float* __restrict__ b1, const float* __restrict__ b2,
    unsigned short* __restrict__ o0, unsigned short* __restrict__ o1, unsigned short* __restrict__ o2)
{
    __shared__ __align__(16) unsigned short Ws[512 * 32];   // 32 KB, linear
    __shared__ __align__(16) unsigned short Ab[64 * 40];    // 5 KB, pad 40
    const int z = blockIdx.y;
    const float* A = (z == 0) ? A0 : (z == 1) ? A1 : A2;
    const unsigned short* W = Wb + (size_t)z * WSEG;
    const float* bias = (z == 0) ? b0 : (z == 1) ? b1 : b2;
    const float bsc = (z == 0) ? QSCALE : 1.0f;
    unsigned short* Cout = (z == 0) ? o0 : (z == 1) ? o1 : o2;

    const int tid = threadIdx.x;
    const int wave = tid >> 6, lane = tid & 63;
    const int lg = lane >> 4, li = lane & 15;
    const int m0 = blockIdx.x * 64;

    f32x4 acc[4][4] = {};

    // W staging: instr i covers rows i*128 + wave*16 + (lane>>2), unit lane&3.
    const unsigned short* gw = W
        + (size_t)((wave << 4) + (lane >> 2)) * 512 + (lane & 3) * 8;
    unsigned short* lW = Ws + wave * 512;   // +4096 elems per instr
    // A staging: thread t covers row t>>3, f32 cols (t&7)*4 (one float4).
    const float* ga = A + (size_t)(m0 + (tid >> 3)) * 512 + (tid & 7) * 4;
    const int ar = tid >> 3;                // A row
    const int au = tid & 7;                 // 8B unit within row

    for (int k0 = 0; k0 < 512; k0 += 32) {
        __syncthreads();
#pragma unroll
        for (int i = 0; i < 4; i++)
            gl16(gw + k0 + (size_t)i * 128 * 512, lW + i * 4096);
        {
            const float4 f = *reinterpret_cast<const float4*>(ga + k0);
            union { unsigned int u[2]; uint2 v; } pk;
            pk.u[0] = cvtpk(f.x, f.y);
            pk.u[1] = cvtpk(f.z, f.w);
            *reinterpret_cast<uint2*>(&Ab[ar * 40 + au * 4]) = pk.v;
        }
        __syncthreads();

        short8v af[4], wf[4];
#pragma unroll
        for (int i = 0; i < 4; i++) {
            af[i] = *reinterpret_cast<const short8v*>(&Ab[(i * 16 + li) * 40 + lg * 8]);
            wf[i] = *reinterpret_cast<const short8v*>(
                &Ws[(wave * 64 + i * 16 + li) * 32 + lg * 8]);
        }
#pragma unroll
        for (int i = 0; i < 4; i++)
#pragma unroll
            for (int j = 0; j < 4; j++)
                acc[i][j] = __builtin_amdgcn_mfma_f32_16x16x32_bf16(af[i], wf[j], acc[i][j], 0, 0, 0);
    }

#pragma unroll
    for (int j = 0; j < 4; j++) {
        const int col = wave * 64 + j * 16 + li;
        const float bb = bias[col] * bsc;
#pragma unroll
        for (int i = 0; i < 4; i++) {
            const int row0 = m0 + i * 16 + lg * 4;
#pragma unroll
            for (int r = 0; r < 4; r++)
                Cout[(size_t)(row0 + r) * 512 + col] = f2bf(acc[i][j][r] + bb);
        }
    }
}

// ---------------------------------------------------------------------------
// bf16 GEMM, f32 output (Wo projection). m97 structure, BK=32, grid (256,4).
// ---------------------------------------------------------------------------
__global__ __launch_bounds__(256) void gemm_out(
    const unsigned short* __restrict__ A, const unsigned short* __restrict__ W,
    const float* __restrict__ bias, float* __restrict__ Cout)
{
    __shared__ __align__(16) unsigned short As[128 * 32];
    __shared__ __align__(16) unsigned short Bs[128 * 32];
    const int tid = threadIdx.x;
    const int wave = tid >> 6, lane = tid & 63;
    const int lg = lane >> 4, li = lane & 15;
    const int m0 = blockIdx.x * 128;
    const int n0 = blockIdx.y * 128;
    const int wr = (wave >> 1) * 64;
    const int wc = (wave & 1) * 64;

    f32x4 acc[4][4] = {};

    const unsigned short* ga = A + (size_t)(m0 + (tid >> 2)) * 512 + (tid & 3) * 8;
    const unsigned short* gb = W + (size_t)(n0 + (tid >> 2)) * 512 + (tid & 3) * 8;
    unsigned short* lA = &As[wave * 512];
    unsigned short* lB = &Bs[wave * 512];

    for (int k0 = 0; k0 < 512; k0 += 32) {
        __syncthreads();
        gl16(ga + k0, lA);
        gl16(ga + k0 + 64 * 512, lA + 2048);
        gl16(gb + k0, lB);
        gl16(gb + k0 + 64 * 512, lB + 2048);
        __syncthreads();

        short8v af[4], bfr[4];
#pragma unroll
        for (int i = 0; i < 4; i++) {
            af[i]  = *reinterpret_cast<const short8v*>(&As[(wr + i * 16 + li) * 32 + lg * 8]);
            bfr[i] = *reinterpret_cast<const short8v*>(&Bs[(wc + i * 16 + li) * 32 + lg * 8]);
        }
#pragma unroll
        for (int i = 0; i < 4; i++)
#pragma unroll
            for (int j = 0; j < 4; j++)
                acc[i][j] = __builtin_amdgcn_mfma_f32_16x16x32_bf16(af[i], bfr[j], acc[i][j], 0, 0, 0);
    }

#pragma unroll
    for (int j = 0; j < 4; j++) {
        const int col = n0 + wc + j * 16 + li;
        const float bb = bias[col];
#pragma unroll
        for (int i = 0; i < 4; i++) {
            const int row0 = m0 + wr + i * 16 + lg * 4;
#pragma unroll
            for (int r = 0; r < 4; r++)
                Cout[(size_t)(row0 + r) * 512 + col] = acc[i][j][r] + bb;
        }
    }
}

// ---------------------------------------------------------------------------
// bf16 flash attention (round-8 verified, unchanged). grid = (4 q-tiles, 512).
// ---------------------------------------------------------------------------
__global__ __launch_bounds__(256) void attn_bf16(
    const unsigned short* __restrict__ qp, const unsigned short* __restrict__ kp,
    const unsigned short* __restrict__ vp, unsigned short* __restrict__ ao)
{
    __shared__ __align__(16) unsigned short Qs[128 * 64];   // linear
    __shared__ __align__(16) unsigned short Ks[64 * 64];    // XOR-swizzled rows
    __shared__ __align__(16) unsigned short Vt[64][68];     // [d][key], pad 68
    __shared__ __align__(16) unsigned short Pl[4][32][72];  // per-wave P [q][key]

    const int tid = threadIdx.x;
    const int wave = tid >> 6, lane = tid & 63;
    const int lg = lane >> 4, li = lane & 15;
    const int n0 = blockIdx.x * 128;
    const int th = blockIdx.y;
    const size_t base = (size_t)(th >> 3) * EMB + (size_t)(th & 7) * HDIM;

    // ---- stage Q (linear), hoist frags ----
    {
        const unsigned short* gq = qp + (size_t)(n0 + (tid >> 3)) * ROWSTRIDE + base + (tid & 7) * 8;
        unsigned short* lq = &Qs[wave * 512];
#pragma unroll
        for (int i = 0; i < 4; i++)
            gl16(gq + (size_t)i * 32 * ROWSTRIDE, lq + i * 2048);
    }
    __syncthreads();
    short8v qf[2][2];
#pragma unroll
    for (int mf = 0; mf < 2; mf++)
#pragma unroll
        for (int kf = 0; kf < 2; kf++)
            qf[mf][kf] = *reinterpret_cast<const short8v*>(
                &Qs[(wave * 32 + mf * 16 + li) * 64 + kf * 32 + lg * 8]);

    // ---- V prefetch (tile 0): 4x4 micro-tile, 4 x global b64 ----
    const int vd0 = (tid & 15) * 4;        // d-quad (consecutive lanes coalesce)
    const int vk0 = (tid >> 4) * 4;        // key-quad
    const unsigned short* gv = vp + base + vd0;
    uint2 vl[4];
#pragma unroll
    for (int i = 0; i < 4; i++)
        vl[i] = *reinterpret_cast<const uint2*>(gv + (size_t)(vk0 + i) * ROWSTRIDE);

    const short8v ones = (short8v)(short)0x3F80;   // bf16 1.0 splat
    f32x4 acc[2][4] = {};
    f32x4 acc_l[2] = {};

    for (int kv = 0; kv < 8; kv++) {
        const int k0 = kv * 64;
        __syncthreads();   // prior tile reads complete

        // stage K (XOR-swizzled source)
        {
            unsigned short* lk = &Ks[wave * 512];
#pragma unroll
            for (int i = 0; i < 2; i++) {
                const int r = (tid >> 3) + i * 32;
                const int srcofs = (((tid & 7) * 8) ^ ((r & 7) * 8));
                gl16(kp + (size_t)(k0 + r) * ROWSTRIDE + base + srcofs, lk + i * 2048);
            }
        }
        // stage V^T: in-reg 4x4 transpose of prefetched micro-tile, b64 writes
#pragma unroll
        for (int dd = 0; dd < 4; dd++) {
            const unsigned int sel = (dd & 1) ? 0x07060302u : 0x05040100u;
            const unsigned int a = (dd < 2) ? vl[0].x : vl[0].y;
            const unsigned int b = (dd < 2) ? vl[1].x : vl[1].y;
            const unsigned int c = (dd < 2) ? vl[2].x : vl[2].y;
            const unsigned int d = (dd < 2) ? vl[3].x : vl[3].y;
            uint2 o;
            o.x = __builtin_amdgcn_perm(b, a, sel);   // [v0[dd], v1[dd]]
            o.y = __builtin_amdgcn_perm(d, c, sel);   // [v2[dd], v3[dd]]
            *reinterpret_cast<uint2*>(&Vt[vd0 + dd][vk0]) = o;
        }
        __syncthreads();   // K (vmcnt) drained, Vt visible

        // prefetch next V tile under compute
        if (kv < 7) {
#pragma unroll
            for (int i = 0; i < 4; i++)
                vl[i] = *reinterpret_cast<const uint2*>(
                    gv + (size_t)(k0 + 64 + vk0 + i) * ROWSTRIDE);
        }

        // ---- QK^T (swapped): s[mf][nf][r] = logit(q=mf*16+li, key=nf*16+lg*4+r)
        f32x4 s[2][4] = {};
#pragma unroll
        for (int nf = 0; nf < 4; nf++) {
            const int key = nf * 16 + li;
#pragma unroll
            for (int kf = 0; kf < 2; kf++) {
                const short8v kfrag = *reinterpret_cast<const short8v*>(
                    &Ks[key * 64 + ((kf * 32 + lg * 8) ^ ((key & 7) * 8))]);
#pragma unroll
                for (int mf = 0; mf < 2; mf++)
                    s[mf][nf] = __builtin_amdgcn_mfma_f32_16x16x32_bf16(kfrag, qf[mf][kf], s[mf][nf], 0, 0, 0);
            }
        }

        // ---- softmax: p = exp2(s); pack pairs; b64 store along keys ----
#pragma unroll
        for (int mf = 0; mf < 2; mf++)
#pragma unroll
            for (int nf = 0; nf < 4; nf++) {
                const float p0 = exp2f(s[mf][nf][0]);
                const float p1 = exp2f(s[mf][nf][1]);
                const float p2 = exp2f(s[mf][nf][2]);
                const float p3 = exp2f(s[mf][nf][3]);
                union { unsigned int u[2]; uint2 v; } pk2;
                pk2.u[0] = cvtpk(p0, p1);
                pk2.u[1] = cvtpk(p2, p3);
                *reinterpret_cast<uint2*>(&Pl[wave][mf * 16 + li][nf * 16 + lg * 4]) = pk2.v;
            }

        // ---- P A-frags (rows=q) + l-sum via ones-MFMA ----
        short8v pf[2][2];
#pragma unroll
        for (int mf = 0; mf < 2; mf++)
#pragma unroll
            for (int kf = 0; kf < 2; kf++)
                pf[mf][kf] = *reinterpret_cast<const short8v*>(
                    &Pl[wave][mf * 16 + li][kf * 32 + lg * 8]);
#pragma unroll
        for (int mf = 0; mf < 2; mf++)
#pragma unroll
            for (int kf = 0; kf < 2; kf++)
                acc_l[mf] = __builtin_amdgcn_mfma_f32_16x16x32_bf16(pf[mf][kf], ones, acc_l[mf], 0, 0, 0);

        // ---- P @ V ----
#pragma unroll
        for (int df = 0; df < 4; df++)
#pragma unroll
            for (int kf = 0; kf < 2; kf++) {
                const short8v vfr = *reinterpret_cast<const short8v*>(
                    &Vt[df * 16 + li][kf * 32 + lg * 8]);
#pragma unroll
                for (int mf = 0; mf < 2; mf++)
                    acc[mf][df] = __builtin_amdgcn_mfma_f32_16x16x32_bf16(pf[mf][kf], vfr, acc[mf][df], 0, 0, 0);
            }
    }

    // ---- epilogue: divide by l, store bf16 ----
#pragma unroll
    for (int mf = 0; mf < 2; mf++) {
#pragma unroll
        for (int r = 0; r < 4; r++) {
            const float linv = 1.0f / acc_l[mf][r];
            const int qrow = n0 + wave * 32 + mf * 16 + lg * 4 + r;
#pragma unroll
            for (int df = 0; df < 4; df++)
                ao[(size_t)qrow * ROWSTRIDE + base + df * 16 + li] = f2bf(acc[mf][df][r] * linv);
        }
    }
}

extern "C" void kernel_launch(void* const* d_in, const int* in_sizes, int n_in,
                              void* d_out, int out_size, void* d_ws, size_t ws_size,
                              hipStream_t stream) {
    const float* values = (const float*)d_in[0];
    const float* keys   = (const float*)d_in[1];
    const float* query  = (const float*)d_in[2];
    const float* Wv = (const float*)d_in[3];
    const float* bv = (const float*)d_in[4];
    const float* Wk = (const float*)d_in[5];
    const float* bk = (const float*)d_in[6];
    const float* Wq = (const float*)d_in[7];
    const float* bq = (const float*)d_in[8];
    const float* Wo = (const float*)d_in[9];
    const float* bo = (const float*)d_in[10];
    float* out = (float*)d_out;

    unsigned short* ws16 = (unsigned short*)d_ws;
    const size_t PLANE = (size_t)MROWS * EMB;
    unsigned short* qb = ws16;                  // projected q/k/v (bf16)
    unsigned short* kb = ws16 + PLANE;
    unsigned short* vb = ws16 + 2 * PLANE;
    unsigned short* ab = ws16 + 3 * PLANE;      // attention output
    unsigned short* wb = ws16 + 4 * PLANE;      // 4 bf16 weight mats

    cvtw<<<dim3(WSEG / 4 / 256, 4), 256, 0, stream>>>(Wq, Wk, Wv, Wo, wb);

    gemm_proj3<<<dim3(MROWS / 64, 3), 512, 0, stream>>>(
        query, keys, values, wb, bq, bk, bv, qb, kb, vb);

    attn_bf16<<<dim3(4, TT * NHEADS), 256, 0, stream>>>(qb, kb, vb, ab);

    gemm_out<<<dim3(MROWS / 128, EMB / 128), 256, 0, stream>>>(
        ab, wb + 3 * WSEG, bo, out);
}

// Round 14
// 222.663 us; speedup vs baseline: 1.1790x; 1.1790x over previous
//
#include <hip/hip_runtime.h>
#include <hip/hip_bf16.h>
#include <math.h>

#define NBATCH 512
#define TT 64
#define EMB 512
#define NHEADS 8
#define HDIM 64
#define MROWS (NBATCH * TT)          // 32768
#define ROWSTRIDE (TT * EMB)         // 32768 elems per batch row of a plane
#define WSEG 262144                  // 512*512 weight elems

// 1/sqrt(512) * log2(e): folded into Wq/bq so attn logits are in log2 domain
static constexpr float QSCALE = 0.0637587140f;

typedef __attribute__((ext_vector_type(8))) short short8v;  // 8 bf16 (4 VGPR)
typedef __attribute__((ext_vector_type(4))) float f32x4;

__device__ __forceinline__ unsigned short f2bf(float x) {
    union { float f; unsigned int u; } v; v.f = x;
    unsigned int r = v.u + 0x7fff + ((v.u >> 16) & 1);   // RNE
    return (unsigned short)(r >> 16);
}

// v_cvt_pk_bf16_f32: packs lo->bits[15:0], hi->bits[31:16], RNE
__device__ __forceinline__ unsigned int cvtpk(float lo, float hi) {
    unsigned int r;
    asm("v_cvt_pk_bf16_f32 %0, %1, %2" : "=v"(r) : "v"(lo), "v"(hi));
    return r;
}

__device__ __forceinline__ void gl16(const void* g, void* l) {
    __builtin_amdgcn_global_load_lds(
        (const __attribute__((address_space(1))) unsigned int*)g,
        (__attribute__((address_space(3))) unsigned int*)l, 16, 0, 0);
}

// ---------------------------------------------------------------------------
// weights fp32 -> bf16 (4 MB); seg 0 (Wq) pre-scaled by QSCALE
// ---------------------------------------------------------------------------
__global__ __launch_bounds__(256) void cvtw(
    const float* __restrict__ w0, const float* __restrict__ w1,
    const float* __restrict__ w2, const float* __restrict__ w3,
    unsigned short* __restrict__ dst)
{
    const int seg = blockIdx.y;
    const float* src = (seg == 0) ? w0 : (seg == 1) ? w1 : (seg == 2) ? w2 : w3;
    const float sc = (seg == 0) ? QSCALE : 1.0f;
    const size_t i = (size_t)blockIdx.x * 256 + threadIdx.x;   // x4 elems
    float4 v = reinterpret_cast<const float4*>(src)[i];
    ushort4 r;
    r.x = f2bf(v.x * sc); r.y = f2bf(v.y * sc); r.z = f2bf(v.z * sc); r.w = f2bf(v.w * sc);
    reinterpret_cast<ushort4*>(dst + (size_t)seg * WSEG)[i] = r;
}

// ---------------------------------------------------------------------------
// Merged q/k/v projections (ROUND-11 form, best measured at 128.6 us).
// FULL-N blocks: one block = 128 m-rows x all 512 n; A read from HBM once.
// 512 thr / 8 waves (2m x 4n), acc[4][8], BK=64, single-buffered.
// ---------------------------------------------------------------------------
__global__ __launch_bounds__(512) void gemm_proj3(
    const float* __restrict__ A0, const float* __restrict__ A1,
    const float* __restrict__ A2, const unsigned short* __restrict__ Wb,
    const float* __restrict__ b0, const float* __restrict__ b1, const float* __restrict__ b2,
    unsigned short* __restrict__ o0, unsigned short* __restrict__ o1, unsigned short* __restrict__ o2)
{
    __shared__ __align__(16) float Asf[128 * 64];            // 32 KB swizzled f32
    __shared__ __align__(16) unsigned short Bs[512 * 64];    // 64 KB bf16
    const int z = blockIdx.y;
    const float* A = (z == 0) ? A0 : (z == 1) ? A1 : A2;
    const unsigned short* W = Wb + (size_t)z * WSEG;
    const float* bias = (z == 0) ? b0 : (z == 1) ? b1 : b2;
    const float bsc = (z == 0) ? QSCALE : 1.0f;
    unsigned short* Cout = (z == 0) ? o0 : (z == 1) ? o1 : o2;

    const int tid = threadIdx.x;
    const int wave = tid >> 6, lane = tid & 63;
    const int lg = lane >> 4, li = lane & 15;
    const int m0 = blockIdx.x * 128;
    const int wm = (wave >> 2) * 64;        // wave row offset (0/64)
    const int wn = (wave & 3) * 128;        // wave col offset (0..384)

    f32x4 acc[4][8] = {};

    const int au = (tid & 15) ^ ((tid >> 4) & 15);
    const float* gaf = A + (size_t)(m0 + (tid >> 4)) * 512 + au * 4;
    float* lA = Asf + wave * 256;
    const unsigned short* gb = W + (size_t)(tid >> 3) * 512 + (tid & 7) * 8;
    unsigned short* lB = Bs + wave * 512;

    for (int k0 = 0; k0 < 512; k0 += 64) {
        __syncthreads();
#pragma unroll
        for (int i = 0; i < 4; i++)
            gl16(gaf + k0 + (size_t)i * 32 * 512, lA + i * 2048);
#pragma unroll
        for (int i = 0; i < 8; i++)
            gl16(gb + k0 + (size_t)i * 64 * 512, lB + i * 4096);
        __syncthreads();

#pragma unroll
        for (int kk = 0; kk < 2; kk++) {
            short8v af[4];
#pragma unroll
            for (int i = 0; i < 4; i++) {
                const int r = wm + i * 16 + li;      // r & 15 == li
                const int lu0 = kk * 8 + lg * 2;
                const float4 fa = *reinterpret_cast<const float4*>(
                    &Asf[r * 64 + (lu0 ^ li) * 4]);
                const float4 fb = *reinterpret_cast<const float4*>(
                    &Asf[r * 64 + ((lu0 + 1) ^ li) * 4]);
                union { unsigned int u[4]; short8v v; } pk;
                pk.u[0] = cvtpk(fa.x, fa.y); pk.u[1] = cvtpk(fa.z, fa.w);
                pk.u[2] = cvtpk(fb.x, fb.y); pk.u[3] = cvtpk(fb.z, fb.w);
                af[i] = pk.v;
            }
#pragma unroll
            for (int j = 0; j < 8; j++) {
                const short8v bfr = *reinterpret_cast<const short8v*>(
                    &Bs[(wn + j * 16 + li) * 64 + kk * 32 + lg * 8]);
#pragma unroll
                for (int i = 0; i < 4; i++)
                    acc[i][j] = __builtin_amdgcn_mfma_f32_16x16x32_bf16(af[i], bfr, acc[i][j], 0, 0, 0);
            }
        }
    }

#pragma unroll
    for (int j = 0; j < 8; j++) {
        const int col = wn + j * 16 + li;
        const float bb = bias[col] * bsc;
#pragma unroll
        for (int i = 0; i < 4; i++) {
            const int row0 = m0 + wm + i * 16 + lg * 4;
#pragma unroll
            for (int r = 0; r < 4; r++)
                Cout[(size_t)(row0 + r) * 512 + col] = f2bf(acc[i][j][r] + bb);
        }
    }
}

// ---------------------------------------------------------------------------
// bf16 GEMM, f32 output (Wo projection). m97 structure, BK=32, grid (256,4).
// ---------------------------------------------------------------------------
__global__ __launch_bounds__(256) void gemm_out(
    const unsigned short* __restrict__ A, const unsigned short* __restrict__ W,
    const float* __restrict__ bias, float* __restrict__ Cout)
{
    __shared__ __align__(16) unsigned short As[128 * 32];
    __shared__ __align__(16) unsigned short Bs[128 * 32];
    const int tid = threadIdx.x;
    const int wave = tid >> 6, lane = tid & 63;
    const int lg = lane >> 4, li = lane & 15;
    const int m0 = blockIdx.x * 128;
    const int n0 = blockIdx.y * 128;
    const int wr = (wave >> 1) * 64;
    const int wc = (wave & 1) * 64;

    f32x4 acc[4][4] = {};

    const unsigned short* ga = A + (size_t)(m0 + (tid >> 2)) * 512 + (tid & 3) * 8;
    const unsigned short* gb = W + (size_t)(n0 + (tid >> 2)) * 512 + (tid & 3) * 8;
    unsigned short* lA = &As[wave * 512];
    unsigned short* lB = &Bs[wave * 512];

    for (int k0 = 0; k0 < 512; k0 += 32) {
        __syncthreads();
        gl16(ga + k0, lA);
        gl16(ga + k0 + 64 * 512, lA + 2048);
        gl16(gb + k0, lB);
        gl16(gb + k0 + 64 * 512, lB + 2048);
        __syncthreads();

        short8v af[4], bfr[4];
#pragma unroll
        for (int i = 0; i < 4; i++) {
            af[i]  = *reinterpret_cast<const short8v*>(&As[(wr + i * 16 + li) * 32 + lg * 8]);
            bfr[i] = *reinterpret_cast<const short8v*>(&Bs[(wc + i * 16 + li) * 32 + lg * 8]);
        }
#pragma unroll
        for (int i = 0; i < 4; i++)
#pragma unroll
            for (int j = 0; j < 4; j++)
                acc[i][j] = __builtin_amdgcn_mfma_f32_16x16x32_bf16(af[i], bfr[j], acc[i][j], 0, 0, 0);
    }

#pragma unroll
    for (int j = 0; j < 4; j++) {
        const int col = n0 + wc + j * 16 + li;
        const float bb = bias[col];
#pragma unroll
        for (int i = 0; i < 4; i++) {
            const int row0 = m0 + wr + i * 16 + lg * 4;
#pragma unroll
            for (int r = 0; r < 4; r++)
                Cout[(size_t)(row0 + r) * 512 + col] = acc[i][j][r] + bb;
        }
    }
}

// ---------------------------------------------------------------------------
// bf16 flash attention v4: QBLK=256. grid = (2 q-tiles of 256, T*H=512),
// 256 thr / 4 waves; each wave owns 64 q-rows (mf = 0..3). KVBLK=64.
// K/V staging and per-fragment algebra IDENTICAL to the verified round-8
// kernel; changes are: (1) Q frags loaded directly global->reg (no Q LDS,
// one-time scatter), (2) mf extended 2->4, (3) K/V frags hoisted to regs
// once per iter, (4) softmax/P-roundtrip/PV processed per-mf through a
// reused per-wave 16-row P buffer. KV re-reads halve (2 blocks per pair).
// ---------------------------------------------------------------------------
__global__ __launch_bounds__(256) void attn_bf16(
    const unsigned short* __restrict__ qp, const unsigned short* __restrict__ kp,
    const unsigned short* __restrict__ vp, unsigned short* __restrict__ ao)
{
    __shared__ __align__(16) unsigned short Ks[64 * 64];    // XOR-swizzled rows
    __shared__ __align__(16) unsigned short Vt[64][68];     // [d][key], pad 68
    __shared__ __align__(16) unsigned short Pl[4][16][72];  // per-wave P chunk

    const int tid = threadIdx.x;
    const int wave = tid >> 6, lane = tid & 63;
    const int lg = lane >> 4, li = lane & 15;
    const int n0 = blockIdx.x * 256;
    const int th = blockIdx.y;
    const size_t base = (size_t)(th >> 3) * EMB + (size_t)(th & 7) * HDIM;

    // ---- Q frags direct from global (one-time scatter; qb is L2/L3-warm) ----
    short8v qf[4][2];
#pragma unroll
    for (int mf = 0; mf < 4; mf++)
#pragma unroll
        for (int kf = 0; kf < 2; kf++)
            qf[mf][kf] = *reinterpret_cast<const short8v*>(
                qp + (size_t)(n0 + wave * 64 + mf * 16 + li) * ROWSTRIDE
                   + base + kf * 32 + lg * 8);

    // ---- V prefetch (tile 0): 4x4 micro-tile, 4 x global b64 ----
    const int vd0 = (tid & 15) * 4;
    const int vk0 = (tid >> 4) * 4;
    const unsigned short* gv = vp + base + vd0;
    uint2 vl[4];
#pragma unroll
    for (int i = 0; i < 4; i++)
        vl[i] = *reinterpret_cast<const uint2*>(gv + (size_t)(vk0 + i) * ROWSTRIDE);

    const short8v ones = (short8v)(short)0x3F80;   // bf16 1.0 splat
    f32x4 acc[4][4] = {};
    f32x4 acc_l[4] = {};

    for (int kv = 0; kv < 8; kv++) {
        const int k0 = kv * 64;
        __syncthreads();   // prior tile reads complete

        // stage K (XOR-swizzled source) — verified pattern
        {
            unsigned short* lk = &Ks[wave * 512];
#pragma unroll
            for (int i = 0; i < 2; i++) {
                const int r = (tid >> 3) + i * 32;
                const int srcofs = (((tid & 7) * 8) ^ ((r & 7) * 8));
                gl16(kp + (size_t)(k0 + r) * ROWSTRIDE + base + srcofs, lk + i * 2048);
            }
        }
        // stage V^T: in-reg 4x4 micro-tile transpose — verified pattern
#pragma unroll
        for (int dd = 0; dd < 4; dd++) {
            const unsigned int sel = (dd & 1) ? 0x07060302u : 0x05040100u;
            const unsigned int a = (dd < 2) ? vl[0].x : vl[0].y;
            const unsigned int b = (dd < 2) ? vl[1].x : vl[1].y;
            const unsigned int c = (dd < 2) ? vl[2].x : vl[2].y;
            const unsigned int d = (dd < 2) ? vl[3].x : vl[3].y;
            uint2 o;
            o.x = __builtin_amdgcn_perm(b, a, sel);
            o.y = __builtin_amdgcn_perm(d, c, sel);
            *reinterpret_cast<uint2*>(&Vt[vd0 + dd][vk0]) = o;
        }
        __syncthreads();   // K (vmcnt) drained, Vt visible

        // prefetch next V tile under compute
        if (kv < 7) {
#pragma unroll
            for (int i = 0; i < 4; i++)
                vl[i] = *reinterpret_cast<const uint2*>(
                    gv + (size_t)(k0 + 64 + vk0 + i) * ROWSTRIDE);
        }

        // hoist K and V frags to regs (read LDS once per iter)
        short8v kfr[4][2], vfr[4][2];
#pragma unroll
        for (int nf = 0; nf < 4; nf++) {
            const int key = nf * 16 + li;
#pragma unroll
            for (int kf = 0; kf < 2; kf++)
                kfr[nf][kf] = *reinterpret_cast<const short8v*>(
                    &Ks[key * 64 + ((kf * 32 + lg * 8) ^ ((key & 7) * 8))]);
        }
#pragma unroll
        for (int df = 0; df < 4; df++)
#pragma unroll
            for (int kf = 0; kf < 2; kf++)
                vfr[df][kf] = *reinterpret_cast<const short8v*>(
                    &Vt[df * 16 + li][kf * 32 + lg * 8]);

        // ---- per-mf: QK^T -> softmax -> P chunk -> l-sum + PV ----
#pragma unroll
        for (int mf = 0; mf < 4; mf++) {
            // QK (swapped): s[nf][r] = logit(q = wave*64+mf*16+li, key = nf*16+lg*4+r)
            f32x4 s[4] = {};
#pragma unroll
            for (int nf = 0; nf < 4; nf++)
#pragma unroll
                for (int kf = 0; kf < 2; kf++)
                    s[nf] = __builtin_amdgcn_mfma_f32_16x16x32_bf16(kfr[nf][kf], qf[mf][kf], s[nf], 0, 0, 0);

            // softmax: p = exp2(s); pack pairs; b64 store along keys
#pragma unroll
            for (int nf = 0; nf < 4; nf++) {
                const float p0 = exp2f(s[nf][0]);
                const float p1 = exp2f(s[nf][1]);
                const float p2 = exp2f(s[nf][2]);
                const float p3 = exp2f(s[nf][3]);
                union { unsigned int u[2]; uint2 v; } pk2;
                pk2.u[0] = cvtpk(p0, p1);
                pk2.u[1] = cvtpk(p2, p3);
                *reinterpret_cast<uint2*>(&Pl[wave][li][nf * 16 + lg * 4]) = pk2.v;
            }

            // P A-frags (rows = q) + l-sum + PV
            short8v pf[2];
#pragma unroll
            for (int kf = 0; kf < 2; kf++)
                pf[kf] = *reinterpret_cast<const short8v*>(
                    &Pl[wave][li][kf * 32 + lg * 8]);
#pragma unroll
            for (int kf = 0; kf < 2; kf++)
                acc_l[mf] = __builtin_amdgcn_mfma_f32_16x16x32_bf16(pf[kf], ones, acc_l[mf], 0, 0, 0);
#pragma unroll
            for (int df = 0; df < 4; df++)
#pragma unroll
                for (int kf = 0; kf < 2; kf++)
                    acc[mf][df] = __builtin_amdgcn_mfma_f32_16x16x32_bf16(pf[kf], vfr[df][kf], acc[mf][df], 0, 0, 0);
        }
    }

    // ---- epilogue: divide by l, store bf16 ----
#pragma unroll
    for (int mf = 0; mf < 4; mf++) {
#pragma unroll
        for (int r = 0; r < 4; r++) {
            const float linv = 1.0f / acc_l[mf][r];
            const int qrow = n0 + wave * 64 + mf * 16 + lg * 4 + r;
#pragma unroll
            for (int df = 0; df < 4; df++)
                ao[(size_t)qrow * ROWSTRIDE + base + df * 16 + li] = f2bf(acc[mf][df][r] * linv);
        }
    }
}

extern "C" void kernel_launch(void* const* d_in, const int* in_sizes, int n_in,
                              void* d_out, int out_size, void* d_ws, size_t ws_size,
                              hipStream_t stream) {
    const float* values = (const float*)d_in[0];
    const float* keys   = (const float*)d_in[1];
    const float* query  = (const float*)d_in[2];
    const float* Wv = (const float*)d_in[3];
    const float* bv = (const float*)d_in[4];
    const float* Wk = (const float*)d_in[5];
    const float* bk = (const float*)d_in[6];
    const float* Wq = (const float*)d_in[7];
    const float* bq = (const float*)d_in[8];
    const float* Wo = (const float*)d_in[9];
    const float* bo = (const float*)d_in[10];
    float* out = (float*)d_out;

    unsigned short* ws16 = (unsigned short*)d_ws;
    const size_t PLANE = (size_t)MROWS * EMB;
    unsigned short* qb = ws16;                  // projected q/k/v (bf16)
    unsigned short* kb = ws16 + PLANE;
    unsigned short* vb = ws16 + 2 * PLANE;
    unsigned short* ab = ws16 + 3 * PLANE;      // attention output
    unsigned short* wb = ws16 + 4 * PLANE;      // 4 bf16 weight mats

    cvtw<<<dim3(WSEG / 4 / 256, 4), 256, 0, stream>>>(Wq, Wk, Wv, Wo, wb);

    gemm_proj3<<<dim3(MROWS / 128, 3), 512, 0, stream>>>(
        query, keys, values, wb, bq, bk, bv, qb, kb, vb);

    attn_bf16<<<dim3(2, TT * NHEADS), 256, 0, stream>>>(qb, kb, vb, ab);

    gemm_out<<<dim3(MROWS / 128, EMB / 128), 256, 0, stream>>>(
        ab, wb + 3 * WSEG, bo, out);
}